// Round 1
// baseline (1612.374 us; speedup 1.0000x reference)
//
#include <hip/hip_runtime.h>

// ---------------- problem dims ----------------
#define NE   200000
#define DC   64
#define DL   256
#define DD   128
#define FEAT 320          // 2*DD + DC
#define IND  449          // FEAT + DD + 1
#define DH   80
#define BB   32
#define TT   64
#define NEV  2048         // BB*TT

typedef __attribute__((ext_vector_type(8))) short  short8;
typedef __attribute__((ext_vector_type(4))) float  floatx4;

__device__ __forceinline__ unsigned short f2bf(float x) {
    unsigned u = __float_as_uint(x);
    u += 0x7fffu + ((u >> 16) & 1u);        // RNE
    return (unsigned short)(u >> 16);
}
__device__ __forceinline__ float sigmoidf_(float x) { return 1.0f / (1.0f + __expf(-x)); }

// ---------------- prep: W_hh^T -> bf16 ----------------
__global__ __launch_bounds__(256)
void transpose_whh(const float* __restrict__ W_hh, unsigned short* __restrict__ whht) {
    int idx = blockIdx.x * 256 + threadIdx.x;     // 32768 = DD*DL
    int d = idx >> 8, l = idx & 255;
    whht[d * DL + l] = f2bf(W_hh[l * DD + d]);
}

// ---------------- prep: Zsum/Zs/Zo from original mem ----------------
__global__ __launch_bounds__(256)
void precompute_z(const int* __restrict__ seq_s, const int* __restrict__ seq_o,
                  const int* __restrict__ seq_r, const float* __restrict__ mem0,
                  const float* __restrict__ rel_emb, const float* __restrict__ W_hidden,
                  float* __restrict__ Zsum, float* __restrict__ Zs, float* __restrict__ Zo) {
    __shared__ float as_[8][DD], ao_[8][DD], ar_[8][DC];
    int e0 = blockIdx.x * 8;
    int tid = threadIdx.x;
    for (int i = tid; i < 8 * DD; i += 256) {
        int r = i >> 7, d = i & 127;
        as_[r][d] = mem0[(size_t)seq_s[e0 + r] * DD + d];
        ao_[r][d] = mem0[(size_t)seq_o[e0 + r] * DD + d];
    }
    for (int i = tid; i < 8 * DC; i += 256) {
        int r = i >> 6, c = i & 63;
        ar_[r][c] = rel_emb[(size_t)seq_r[e0 + r] * DC + c];
    }
    __syncthreads();
    int l = tid;  // 0..255
    float accs[8] = {0}, acco[8] = {0}, accr[8] = {0};
    for (int d = 0; d < DD; ++d) {
        float w1 = W_hidden[d * DL + l];
        float w2 = W_hidden[(DD + d) * DL + l];
#pragma unroll
        for (int r = 0; r < 8; ++r) { accs[r] += as_[r][d] * w1; acco[r] += ao_[r][d] * w2; }
    }
    for (int c = 0; c < DC; ++c) {
        float w3 = W_hidden[(2 * DD + c) * DL + l];
#pragma unroll
        for (int r = 0; r < 8; ++r) accr[r] += ar_[r][c] * w3;
    }
    for (int r = 0; r < 8; ++r) {
        size_t e = (size_t)(e0 + r) * DL + l;
        Zs[e] = accs[r]; Zo[e] = acco[r];
        Zsum[e] = accs[r] + acco[r] + accr[r];
    }
}

// ---------------- phase 1: sequential scan (single workgroup) ----------------
__global__ __launch_bounds__(512)
void phase1(const int* __restrict__ seq_s, const int* __restrict__ seq_o,
            const int* __restrict__ seq_r, const float* __restrict__ seq_t,
            const float* __restrict__ rel_emb, const float* __restrict__ W_hidden,
            const float* __restrict__ W_st, const float* __restrict__ W_ot,
            const float* __restrict__ Zsum, const float* __restrict__ Zs,
            const float* __restrict__ Zo, const unsigned short* __restrict__ whht,
            float* __restrict__ memo, float* __restrict__ lt,
            int* __restrict__ dirty, float* __restrict__ evt) {
    __shared__ unsigned short h_bf[BB * DL];      // bf16 h, XOR-swizzled groups of 8
    __shared__ float ns_[BB * 132];               // new_s, padded stride
    __shared__ float no_[BB * 132];               // new_o
    __shared__ int   sS[BB], sO[BB], sR[BB];
    __shared__ float sT[BB], sDs[BB], sDo[BB];
    __shared__ int   sdS[BB], sdO[BB];
    __shared__ int   wS[BB], wO[BB];

    const int tid  = threadIdx.x;
    const int lane = tid & 63;
    const int wv   = tid >> 6;         // 0..7
    const int mtile = wv >> 2;         // 0..1
    const int nt0   = (wv & 3) * 2;    // ntiles nt0, nt0+1
    const int mrow  = lane & 15;
    const int quad  = lane >> 4;

    // Preload B fragments (W_hh^T bf16) for 2 N-tiles x 8 K-steps: stays in regs all steps.
    short8 bfrag[2][8];
#pragma unroll
    for (int nt = 0; nt < 2; ++nt) {
        int d = (nt0 + nt) * 16 + mrow;
#pragma unroll
        for (int ks = 0; ks < 8; ++ks)
            bfrag[nt][ks] = *(const short8*)&whht[d * DL + ks * 32 + quad * 8];
    }

    for (int t = 0; t < TT; ++t) {
        // ---- A: per-b scalars (reads previous step's lt/dirty) ----
        if (tid < BB) {
            int b = tid;
            int s = seq_s[b * TT + t];
            int o = seq_o[b * TT + t];
            sS[b] = s; sO[b] = o; sR[b] = seq_r[b * TT + t];
            float tv = seq_t[b * TT + t];
            sT[b] = tv;
            sDs[b] = tv - lt[s];
            sDo[b] = tv - lt[o];
            sdS[b] = dirty[s];
            sdO[b] = dirty[o];
        }
        __syncthreads();

        // ---- B: z = Zsum (+ dirty fixups), h = sigmoid(z) -> bf16 swizzled LDS ----
        {
            int b = tid >> 4;
            int j = tid & 15;           // 16 consecutive l's
            int e = b * TT + t;
            float z[16];
            const float* zsum = &Zsum[(size_t)e * DL + j * 16];
#pragma unroll
            for (int i = 0; i < 16; ++i) z[i] = zsum[i];
            if (sdS[b]) {
                const float* zs = &Zs[(size_t)e * DL + j * 16];
                const float* mr = &memo[(size_t)sS[b] * DD];
                float fr[16];
#pragma unroll
                for (int i = 0; i < 16; ++i) fr[i] = -zs[i];
                for (int d = 0; d < DD; ++d) {
                    float a = mr[d];
                    const float* wr = &W_hidden[d * DL + j * 16];
#pragma unroll
                    for (int i = 0; i < 16; ++i) fr[i] += a * wr[i];
                }
#pragma unroll
                for (int i = 0; i < 16; ++i) z[i] += fr[i];
            }
            if (sdO[b]) {
                const float* zo = &Zo[(size_t)e * DL + j * 16];
                const float* mr = &memo[(size_t)sO[b] * DD];
                float fr[16];
#pragma unroll
                for (int i = 0; i < 16; ++i) fr[i] = -zo[i];
                for (int d = 0; d < DD; ++d) {
                    float a = mr[d];
                    const float* wr = &W_hidden[(DD + d) * DL + j * 16];
#pragma unroll
                    for (int i = 0; i < 16; ++i) fr[i] += a * wr[i];
                }
#pragma unroll
                for (int i = 0; i < 16; ++i) z[i] += fr[i];
            }
            unsigned short hv[16];
#pragma unroll
            for (int i = 0; i < 16; ++i) hv[i] = f2bf(sigmoidf_(z[i]));
            int g0 = (2 * j) ^ (b & 7);
            int g1 = (2 * j + 1) ^ (b & 7);
            short8 v0, v1;
#pragma unroll
            for (int i = 0; i < 8; ++i) { v0[i] = (short)hv[i]; v1[i] = (short)hv[8 + i]; }
            *(short8*)&h_bf[b * DL + g0 * 8] = v0;
            *(short8*)&h_bf[b * DL + g1 * 8] = v1;
        }
        __syncthreads();

        // ---- C: hh = h @ W_hh via bf16 MFMA; new_s/new_o = sigmoid(dt*W + hh) ----
        {
            floatx4 acc0 = {0.f, 0.f, 0.f, 0.f}, acc1 = {0.f, 0.f, 0.f, 0.f};
            int ab = mtile * 16 + mrow;
#pragma unroll
            for (int ks = 0; ks < 8; ++ks) {
                int gp = (ks * 4 + quad) ^ (ab & 7);
                short8 afrag = *(const short8*)&h_bf[ab * DL + gp * 8];
                acc0 = __builtin_amdgcn_mfma_f32_16x16x32_bf16(afrag, bfrag[0][ks], acc0, 0, 0, 0);
                acc1 = __builtin_amdgcn_mfma_f32_16x16x32_bf16(afrag, bfrag[1][ks], acc1, 0, 0, 0);
            }
#pragma unroll
            for (int nt = 0; nt < 2; ++nt) {
                floatx4 acc = nt ? acc1 : acc0;
                int d = (nt0 + nt) * 16 + mrow;
                float wst = W_st[d], wot = W_ot[d];
#pragma unroll
                for (int reg = 0; reg < 4; ++reg) {
                    int b = mtile * 16 + quad * 4 + reg;
                    float hh = acc[reg];
                    ns_[b * 132 + d] = sigmoidf_(sDs[b] * wst + hh);
                    no_[b * 132 + d] = sigmoidf_(sDo[b] * wot + hh);
                }
            }
        }
        // ---- dup resolution (last b wins) + dirty marking ----
        if (tid < 2 * BB) {
            int b = tid & 31;
            const int* arr = (tid < BB) ? sS : sO;
            int v = arr[b];
            int w = 1;
            for (int b2 = b + 1; b2 < BB; ++b2) if (arr[b2] == v) { w = 0; break; }
            if (tid < BB) wS[b] = w; else wO[b] = w;
            dirty[v] = 1;
        }
        __syncthreads();

        // ---- s-scatter (mem + lt) ----
        {
            int b = tid >> 4, j = tid & 15;
            if (wS[b]) {
                floatx4* dst = (floatx4*)&memo[(size_t)sS[b] * DD];
                const float* src = &ns_[b * 132];
                dst[j * 2]     = *(const floatx4*)&src[j * 8];
                dst[j * 2 + 1] = *(const floatx4*)&src[j * 8 + 4];
                if (j == 0) lt[sS[b]] = sT[b];
            }
        }
        __syncthreads();

        // ---- o-scatter (wins over s) + evt write ----
        {
            int b = tid >> 4, j = tid & 15;
            if (wO[b]) {
                floatx4* dst = (floatx4*)&memo[(size_t)sO[b] * DD];
                const float* src = &no_[b * 132];
                dst[j * 2]     = *(const floatx4*)&src[j * 8];
                dst[j * 2 + 1] = *(const floatx4*)&src[j * 8 + 4];
                if (j == 0) lt[sO[b]] = sT[b];
            }
            float* ev = &evt[(size_t)(b * TT + t) * FEAT];
            const float* rr = &rel_emb[(size_t)sR[b] * DC];
            for (int f = j; f < FEAT; f += 16) {
                float v;
                if (f < DD)            v = ns_[b * 132 + f];
                else if (f < 2 * DD)   v = no_[b * 132 + (f - DD)];
                else                   v = rr[f - 2 * DD];
                ev[f] = v;
            }
        }
        __syncthreads();
    }
}

// ---------------- phase 2 ----------------
__global__ __launch_bounds__(128)
void build_e(const float* __restrict__ src, const float* __restrict__ seq_t,
             float* __restrict__ ebuf) {
    int e = blockIdx.x;
    float tv = seq_t[e];
    const float* s = &src[(size_t)e * FEAT];
    float* dst = &ebuf[(size_t)e * IND];
    for (int f = threadIdx.x; f < IND; f += 128) {
        float v;
        if (f < FEAT) v = s[f];
        else if (f < FEAT + DD) {
            int d = f - FEAT;
            float denom = __powf(10000.0f, (float)d);   // inf for d>=10 -> norm 0 (matches ref)
            v = sinf(tv * (1.0f / denom));
        } else v = 1.0f;
        dst[f] = v;
    }
}

__global__ __launch_bounds__(256)
void proj(const float* __restrict__ ebuf, const float* __restrict__ Wq,
          const float* __restrict__ Wk, const float* __restrict__ Wv,
          float* __restrict__ q, float* __restrict__ k, float* __restrict__ v) {
    __shared__ float at[32][IND];
    int tid = threadIdx.x;
    int r0b = blockIdx.x * 32;
    for (int i = tid; i < 32 * IND; i += 256) {
        int r = i / IND, c = i - r * IND;
        at[r][c] = ebuf[(size_t)(r0b + r) * IND + c];
    }
    __syncthreads();
    const float* W = (blockIdx.z == 0) ? Wq : (blockIdx.z == 1) ? Wk : Wv;
    float* out = (blockIdx.z == 0) ? q : (blockIdx.z == 1) ? k : v;
    int colg = tid & 15, rowg = tid >> 4;
    int c0 = blockIdx.y * 64 + colg * 4;
    int r0 = rowg * 2;
    floatx4 acc0 = {0.f, 0.f, 0.f, 0.f}, acc1 = {0.f, 0.f, 0.f, 0.f};
    for (int kk = 0; kk < IND; ++kk) {
        floatx4 w = *(const floatx4*)&W[(size_t)kk * FEAT + c0];
        float a0 = at[r0][kk], a1 = at[r0 + 1][kk];
        acc0 += a0 * w;
        acc1 += a1 * w;
    }
    *(floatx4*)&out[(size_t)(r0b + r0) * FEAT + c0]     = acc0;
    *(floatx4*)&out[(size_t)(r0b + r0 + 1) * FEAT + c0] = acc1;
}

__global__ __launch_bounds__(256)
void attn(const float* __restrict__ q, const float* __restrict__ k,
          const float* __restrict__ v, float* __restrict__ ao) {
    __shared__ float qs[TT][DH], ks[TT][DH], vs[TT][DH];
    __shared__ float sc[TT][TT + 1];
    int bh = blockIdx.x;
    int b = bh >> 2, h = bh & 3;
    int tid = threadIdx.x;
    for (int i = tid; i < TT * DH; i += 256) {
        int r = i / DH, d = i - r * DH;
        size_t base = (size_t)(b * TT + r) * FEAT + h * DH + d;
        qs[r][d] = q[base]; ks[r][d] = k[base]; vs[r][d] = v[base];
    }
    __syncthreads();
    const float scale = 0.11180339887498949f;   // 1/sqrt(80)
    for (int idx = tid; idx < TT * TT; idx += 256) {
        int i = idx >> 6, j = idx & 63;
        float s = 0.f;
        for (int d = 0; d < DH; ++d) s += qs[i][d] * ks[j][d];
        sc[i][j] = s * scale;
    }
    __syncthreads();
    if (tid < TT) {
        int i = tid;
        if (i == 0) {
            for (int j = 0; j < TT; ++j) sc[0][j] = 0.0f;
        } else {
            float m = -1e30f;
            for (int j = 0; j < i; ++j) m = fmaxf(m, sc[i][j]);
            float sum = 0.f;
            for (int j = 0; j < i; ++j) { float p = __expf(sc[i][j] - m); sc[i][j] = p; sum += p; }
            float inv = 1.0f / sum;
            for (int j = 0; j < i; ++j) sc[i][j] *= inv;
            for (int j = i; j < TT; ++j) sc[i][j] = 0.0f;
        }
    }
    __syncthreads();
    for (int idx = tid; idx < TT * DH; idx += 256) {
        int i = idx / DH, d = idx - i * DH;
        float s = 0.f;
        for (int j = 0; j < TT; ++j) s += sc[i][j] * vs[j][d];
        ao[(size_t)(b * TT + i) * FEAT + h * DH + d] = s;
    }
}

__global__ __launch_bounds__(256)
void outproj(const float* __restrict__ ain, const float* __restrict__ Wo,
             const float* __restrict__ resid, float* __restrict__ xout) {
    __shared__ float at[32][FEAT];
    int tid = threadIdx.x;
    int r0b = blockIdx.x * 32;
    for (int i = tid; i < 32 * FEAT; i += 256) {
        int r = i / FEAT, c = i - r * FEAT;
        at[r][c] = ain[(size_t)(r0b + r) * FEAT + c];
    }
    __syncthreads();
    int colg = tid & 15, rowg = tid >> 4;
    int c0 = blockIdx.y * 64 + colg * 4;
    int r0 = rowg * 2;
    floatx4 acc0 = {0.f, 0.f, 0.f, 0.f}, acc1 = {0.f, 0.f, 0.f, 0.f};
    for (int kk = 0; kk < FEAT; ++kk) {
        floatx4 w = *(const floatx4*)&Wo[(size_t)kk * FEAT + c0];
        float a0 = at[r0][kk], a1 = at[r0 + 1][kk];
        acc0 += a0 * w;
        acc1 += a1 * w;
    }
#pragma unroll
    for (int rr = 0; rr < 2; ++rr) {
        int row = r0b + r0 + rr;
        floatx4 a = rr ? acc1 : acc0;
        floatx4 res = *(const floatx4*)&resid[(size_t)row * FEAT + c0];
        floatx4 o;
#pragma unroll
        for (int i = 0; i < 4; ++i) o[i] = res[i] + tanhf(a[i]);
        *(floatx4*)&xout[(size_t)row * FEAT + c0] = o;
    }
}

__global__ __launch_bounds__(128)
void score_k(const float* __restrict__ x, const float* __restrict__ W1,
             const float* __restrict__ b1, const float* __restrict__ W2,
             const float* __restrict__ b2, float* __restrict__ lam_out,
             float* __restrict__ lossbuf) {
    __shared__ float xr[FEAT];
    __shared__ float red[2];
    int e = blockIdx.x;
    int tid = threadIdx.x;
    for (int f = tid; f < FEAT; f += 128) xr[f] = x[(size_t)e * FEAT + f];
    __syncthreads();
    int d = tid;
    float acc = b1[d];
    for (int kk = 0; kk < FEAT; ++kk) acc += xr[kk] * W1[kk * DD + d];
    acc = fmaxf(acc, 0.0f) * W2[d];
    for (int off = 32; off; off >>= 1) acc += __shfl_down(acc, off, 64);
    if ((tid & 63) == 0) red[tid >> 6] = acc;
    __syncthreads();
    if (tid == 0) {
        float s = red[0] + red[1] + b2[0];
        float lam = fmaxf(s, 0.0f) + log1pf(expf(-fabsf(s)));   // softplus
        lam_out[e] = lam;
        lossbuf[e] = -logf(lam + 1e-8f);
    }
}

__global__ __launch_bounds__(1024)
void loss_reduce(const float* __restrict__ lossbuf, float* __restrict__ out0) {
    __shared__ float red[16];
    int tid = threadIdx.x;
    float s = 0.f;
    for (int i = tid; i < NEV; i += 1024) s += lossbuf[i];
    for (int off = 32; off; off >>= 1) s += __shfl_down(s, off, 64);
    if ((tid & 63) == 0) red[tid >> 6] = s;
    __syncthreads();
    if (tid == 0) {
        float tot = 0.f;
        for (int i = 0; i < 16; ++i) tot += red[i];
        out0[0] = tot * (1.0f / 2048.0f);
    }
}

// ---------------- launch ----------------
extern "C" void kernel_launch(void* const* d_in, const int* in_sizes, int n_in,
                              void* d_out, int out_size, void* d_ws, size_t ws_size,
                              hipStream_t stream) {
    const int*   seq_s = (const int*)d_in[0];
    const int*   seq_o = (const int*)d_in[1];
    const int*   seq_r = (const int*)d_in[2];
    const float* seq_t = (const float*)d_in[3];
    const float* mem0  = (const float*)d_in[4];
    const float* lt0   = (const float*)d_in[5];
    const float* rel   = (const float*)d_in[6];
    const float* W_hidden = (const float*)d_in[7];
    const float* W_hh  = (const float*)d_in[8];
    const float* W_st  = (const float*)d_in[9];
    const float* W_ot  = (const float*)d_in[10];
    const float* Wq    = (const float*)d_in[11];
    const float* Wk    = (const float*)d_in[12];
    const float* Wv    = (const float*)d_in[13];
    const float* Wo    = (const float*)d_in[14];
    const float* sW1   = (const float*)d_in[15];
    const float* sb1   = (const float*)d_in[16];
    const float* sW2   = (const float*)d_in[17];
    const float* sb2   = (const float*)d_in[18];

    float* out      = (float*)d_out;
    float* out_lam  = out + 1;
    float* out_mem  = out + 2049;
    float* out_lt   = out + 2049 + (size_t)NE * DD;

    float* ws = (float*)d_ws;
    float* evt   = ws;                       // 655360
    float* xbuf  = ws + 655360;              // 655360
    float* Zsum  = ws + 1310720;             // 524288 }  Z region reused as ebuf
    float* Zs    = ws + 1835008;             // 524288 }  in phase 2 (1.57M >= 919552)
    float* Zo    = ws + 2359296;             // 524288 }
    float* ebuf  = ws + 1310720;
    float* qbuf  = ws + 2883584;             // 655360
    float* kbuf  = ws + 3538944;             // 655360
    float* vbuf  = ws + 4194304;             // 655360
    float* aobuf = ws + 4849664;             // 655360
    float* lossb = ws + 5505024;             // 2048
    unsigned short* whht = (unsigned short*)(ws + 5507072);   // DD*DL bf16
    int*   dirty = (int*)(ws + 5523456);     // NE ints

    // Materialize mem / latest_time outputs (updated in place by phase1).
    hipMemcpyAsync(out_mem, mem0, (size_t)NE * DD * sizeof(float), hipMemcpyDeviceToDevice, stream);
    hipMemcpyAsync(out_lt,  lt0,  (size_t)NE * sizeof(float),      hipMemcpyDeviceToDevice, stream);
    hipMemsetAsync(dirty, 0, (size_t)NE * sizeof(int), stream);

    transpose_whh<<<128, 256, 0, stream>>>(W_hh, whht);
    precompute_z<<<NEV / 8, 256, 0, stream>>>(seq_s, seq_o, seq_r, mem0, rel, W_hidden,
                                              Zsum, Zs, Zo);
    phase1<<<1, 512, 0, stream>>>(seq_s, seq_o, seq_r, seq_t, rel, W_hidden, W_st, W_ot,
                                  Zsum, Zs, Zo, whht, out_mem, out_lt, dirty, evt);

    for (int l = 0; l < 2; ++l) {
        const float* src = l ? xbuf : evt;
        build_e<<<NEV, 128, 0, stream>>>(src, seq_t, ebuf);
        proj<<<dim3(64, 5, 3), 256, 0, stream>>>(ebuf,
                                                 Wq + (size_t)l * IND * FEAT,
                                                 Wk + (size_t)l * IND * FEAT,
                                                 Wv + (size_t)l * IND * FEAT,
                                                 qbuf, kbuf, vbuf);
        attn<<<128, 256, 0, stream>>>(qbuf, kbuf, vbuf, aobuf);
        outproj<<<dim3(64, 5), 256, 0, stream>>>(aobuf, Wo + (size_t)l * FEAT * FEAT, src, xbuf);
    }
    score_k<<<NEV, 128, 0, stream>>>(xbuf, sW1, sb1, sW2, sb2, out_lam, lossb);
    loss_reduce<<<1, 1024, 0, stream>>>(lossb, out);
}